// Round 3
// baseline (442.948 us; speedup 1.0000x reference)
//
#include <hip/hip_runtime.h>

// FastMaskedDense1D.update_site  — skinny GEMM  y = A @ K + bias[index]
//   A: (8192 batch, 4800 k)  from cache[:, :299, :] with row 299 <- inputs
//   K: (4800, 16)            strided slice of kernel (row stride 8192 floats)
// Memory-bound: 157 MB A-read @ 6.3 TB/s => ~25 us floor.
//
// R1: packed K into contiguous ws buffer (killed the 32KB-stride L2 set-thrash).
// R2: K chunk in LDS, 512-thread blocks, 16 waves/CU        (fmd ~135 -> ~60 us)
// R3: LDS pipe was the limiter (~35 us/CU: 2x ds_read_b32 + 2x ds_read_b128 per
//     1024 lane-MACs; K amplified 8x). Now: each lane owns 4 rows x 16 features
//     (K b128 reused 4x), waves are a pure 8-way k-split, and A bypasses LDS
//     entirely — read global->reg, coalesced 64B segments, each element touched
//     by exactly one lane, prefetched one chunk ahead. LDS ~15 us < HBM ~25 us.

#define EXCLUSIVE 1
#define SIZEV     512
#define NF        16
#define NIF       16
#define KROW      (SIZEV * NF)    // kernel row stride in floats (8192)
#define CROW      (SIZEV * NIF)   // cache per-batch stride in floats (8192)
#define MB        16              // batch rows per block
#define KCH       256             // k-rows per LDS chunk
#define SK        20              // K LDS row stride (words): 16B-aligned, 2-way max (free)
#define NW        8               // waves per block

__device__ __forceinline__ void fma4(float4& a, float s, float4 b) {
    a.x = fmaf(s, b.x, a.x);
    a.y = fmaf(s, b.y, a.y);
    a.z = fmaf(s, b.z, a.z);
    a.w = fmaf(s, b.w, a.w);
}

__device__ __forceinline__ float4 red4(float4 v, int m) {
    v.x += __shfl_xor(v.x, m, 64);
    v.y += __shfl_xor(v.y, m, 64);
    v.z += __shfl_xor(v.z, m, 64);
    v.w += __shfl_xor(v.w, m, 64);
    return v;
}

// Gather the used K slice into a dense (rows, 16) buffer; zero-pad to the KCH
// boundary so fmd's over-staging of the last chunk never reads poison.
__global__ __launch_bounds__(256) void pack_k(
    const float* __restrict__ kern,
    const int*   __restrict__ idxp,
    float*       __restrict__ kp)
{
    const int index = *idxp;
    const int jc = index - EXCLUSIVE + 1;
    const int KT = (jc > 0) ? jc * NIF : 0;            // valid packed rows
    const int KTpad = (KT + KCH - 1) & ~(KCH - 1);     // staged reach
    const int t  = blockIdx.x * blockDim.x + threadIdx.x;
    const int r  = t >> 2;                             // k-row
    const int q  = t & 3;                              // float4 within the row
    if (r < KTpad) {
        float4 v = {0.f, 0.f, 0.f, 0.f};
        if (r < KT)
            v = *(const float4*)(kern + (size_t)r * KROW + (size_t)index * NF + 4 * q);
        *(float4*)(kp + (size_t)r * NF + 4 * q) = v;
    }
}

__global__ __launch_bounds__(512, 4) void fmd_kernel(
    const float* __restrict__ inputs,   // (B, 16)
    const float* __restrict__ cache,    // (B, 512, 16)
    const float* __restrict__ kp,       // packed K: (KTpad, 16) in workspace
    const float* __restrict__ bias,     // (512, 16)
    const int*   __restrict__ idxp,     // scalar
    float*       __restrict__ out)      // (B, 16)
{
    __shared__ float Kl[2][KCH * SK];   // 40 KB: double-buffered K chunk
    __shared__ float Red[NW * MB * NF]; // 8 KB: cross-wave combine

    const int index = *idxp;
    const int jc = index - EXCLUSIVE + 1;
    const int KM = (jc > 0) ? (jc - 1) * NIF : 0;   // cache-sourced k count (mult of 16)
    const int NC = (KM + KCH - 1) / KCH;

    const int tid  = threadIdx.x;
    const int lane = tid & 63;
    const int ks   = tid >> 6;      // wave 0..7 = pure k-split
    const int kq   = lane & 15;     // k-slice within 16
    const int rq   = lane >> 4;     // row group 0..3 (4 rows each)
    const int row0 = blockIdx.x * MB;

    // K staging map: thread stages row tid>>1, quads 2*(tid&1), 2*(tid&1)+1
    const int srow = tid >> 1;
    const int sq   = (tid & 1) * 2;

    float4 acc[4][4];
    #pragma unroll
    for (int r = 0; r < 4; ++r)
        #pragma unroll
        for (int q = 0; q < 4; ++q)
            acc[r][q] = make_float4(0.f, 0.f, 0.f, 0.f);

    const float4* kpv = (const float4*)kp;
    // lane's A base: rows row0+rq*4 .. +3, col kq + 16*ks (+ k0 + 128*t later)
    const float* Abase = cache + (size_t)(row0 + rq * 4) * CROW + kq + 16 * ks;

    float4 st0, st1;          // staged K for next chunk
    float  aR[2][4], aN[2][4]; // A for current / next chunk (global->reg prefetch)

    if (NC > 0) {
        // ---- prolog: stage chunk 0 (K -> LDS buf0, A -> regs) ----
        st0 = kpv[(size_t)4 * srow + sq];
        st1 = kpv[(size_t)4 * srow + sq + 1];
        *(float4*)&Kl[0][srow * SK + 4 * sq]       = st0;
        *(float4*)&Kl[0][srow * SK + 4 * (sq + 1)] = st1;
        #pragma unroll
        for (int t = 0; t < 2; ++t)
            #pragma unroll
            for (int r = 0; r < 4; ++r)
                aR[t][r] = Abase[(size_t)r * CROW + 128 * t];   // in-bounds: col < 8192 always

        for (int c = 0; c < NC; ++c) {
            const int k0 = c * KCH;
            if (c + 1 < NC) {
                const int kn = k0 + KCH;
                st0 = kpv[(size_t)4 * (kn + srow) + sq];
                st1 = kpv[(size_t)4 * (kn + srow) + sq + 1];
                #pragma unroll
                for (int t = 0; t < 2; ++t)
                    #pragma unroll
                    for (int r = 0; r < 4; ++r)
                        aN[t][r] = Abase[(size_t)r * CROW + kn + 128 * t];
            }
            __syncthreads();   // chunk-c K writes visible; prev readers done with buf c+1

            const int buf  = c & 1;
            const int kend = min(KCH, KM - k0);     // multiple of 16
            const float* Kb = &Kl[buf][0];

            #pragma unroll
            for (int t = 0; t < 2; ++t) {
                const int sb = 16 * ks + 128 * t;   // this wave's stripe base in chunk
                if (sb < kend) {
                    const float* Kp = Kb + (kq + sb) * SK;
                    float4 kv0 = *(const float4*)(Kp);
                    float4 kv1 = *(const float4*)(Kp + 4);
                    float4 kv2 = *(const float4*)(Kp + 8);
                    float4 kv3 = *(const float4*)(Kp + 12);
                    #pragma unroll
                    for (int r = 0; r < 4; ++r) {
                        const float a = aR[t][r];
                        fma4(acc[r][0], a, kv0);
                        fma4(acc[r][1], a, kv1);
                        fma4(acc[r][2], a, kv2);
                        fma4(acc[r][3], a, kv3);
                    }
                }
            }

            if (c + 1 < NC) {
                const int b2 = (c + 1) & 1;
                *(float4*)&Kl[b2][srow * SK + 4 * sq]       = st0;
                *(float4*)&Kl[b2][srow * SK + 4 * (sq + 1)] = st1;
                #pragma unroll
                for (int t = 0; t < 2; ++t)
                    #pragma unroll
                    for (int r = 0; r < 4; ++r)
                        aR[t][r] = aN[t][r];
            }
        }
    }

    // ---- epilogue: row j = jc-1 comes from `inputs` (ks==0 waves only) ----
    if (jc > 0 && ks == 0) {
        const float* kg = kp + (size_t)((jc - 1) * NIF + kq) * NF;
        float4 kv0 = *(const float4*)(kg);
        float4 kv1 = *(const float4*)(kg + 4);
        float4 kv2 = *(const float4*)(kg + 8);
        float4 kv3 = *(const float4*)(kg + 12);
        #pragma unroll
        for (int r = 0; r < 4; ++r) {
            const float a = inputs[(size_t)(row0 + rq * 4 + r) * NIF + kq];
            fma4(acc[r][0], a, kv0);
            fma4(acc[r][1], a, kv1);
            fma4(acc[r][2], a, kv2);
            fma4(acc[r][3], a, kv3);
        }
    }

    // ---- butterfly reduce over the 16 kq lanes (all lanes end with full sums) ----
    #pragma unroll
    for (int m = 1; m <= 8; m <<= 1)
        #pragma unroll
        for (int r = 0; r < 4; ++r)
            #pragma unroll
            for (int q = 0; q < 4; ++q)
                acc[r][q] = red4(acc[r][q], m);

    // ---- each lane writes one float4: row rq*4+(kq>>2), feature quad kq&3 ----
    // (static-index select to keep acc in registers)
    float4 v = acc[0][0];
    #pragma unroll
    for (int r = 0; r < 4; ++r)
        #pragma unroll
        for (int q = 0; q < 4; ++q)
            if ((kq >> 2) == r && (kq & 3) == q) v = acc[r][q];
    {
        const int row  = rq * 4 + (kq >> 2);
        const int quad = kq & 3;
        *(float4*)&Red[ks * (MB * NF) + row * NF + 4 * quad] = v;
    }
    __syncthreads();

    // ---- combine 8 waves + bias, store ----
    if (tid < MB * NF) {
        const int f = tid & 15;
        float s = bias[(size_t)index * NF + f];
        #pragma unroll
        for (int ww = 0; ww < NW; ++ww)
            s += Red[ww * (MB * NF) + tid];
        out[(size_t)row0 * NF + tid] = s;
    }
}

extern "C" void kernel_launch(void* const* d_in, const int* in_sizes, int n_in,
                              void* d_out, int out_size, void* d_ws, size_t ws_size,
                              hipStream_t stream) {
    const float* inputs = (const float*)d_in[0];
    const float* cache  = (const float*)d_in[1];
    const float* kern   = (const float*)d_in[2];
    const float* bias   = (const float*)d_in[3];
    const int*   idxp   = (const int*)d_in[4];
    float*       out    = (float*)d_out;
    float*       kp     = (float*)d_ws;          // packed K, max 8192*16*4 = 512 KB

    const int batch = in_sizes[0] / NIF;         // 8192
    const int grid  = batch / MB;                // 512 blocks (2/CU, 16 waves/CU)

    pack_k<<<(SIZEV * NIF * 4) / 256, 256, 0, stream>>>(kern, idxp, kp);
    fmd_kernel<<<grid, 512, 0, stream>>>(inputs, cache, kp, bias, idxp, out);
}